// Round 6
// baseline (300.666 us; speedup 1.0000x reference)
//
#include <hip/hip_runtime.h>

// ---------------------------------------------------------------------------
// GAT edge-average layer, MI355X.
// Phase 0 : k_wconv — Wf (f32) -> W' split-bf16 tables wh/wl [256][128]
// Phase 1 : k_transform — MFMA bf16x3, A=W'/B=x (swapped: float4 C-stores).
//           1 node-tile(16)/block, 4 waves each own 4 col-tiles -> 12.2
//           waves/SIMD supplied. U=x@Wf1.T, Vb=x@Wf2.T+bf, p/q fused (f64).
// Phase 2 : CSR build — histogram tgt, 2-level exclusive scan, scatter src
// Phase 3 : k_node — 32 lanes/node, 4-edge unrolled gather, f64 accum.
// ---------------------------------------------------------------------------

typedef short bf16x8 __attribute__((ext_vector_type(8)));
typedef float f32x4  __attribute__((ext_vector_type(4)));

__device__ inline short f32_to_bf16_rne(float f) {
    unsigned u = __float_as_uint(f);
    unsigned r = u + 0x7fffu + ((u >> 16) & 1u);
    return (short)(r >> 16);
}
__device__ inline float bf16s_to_f32(short s) {
    return __uint_as_float(((unsigned)(unsigned short)s) << 16);
}

// W'[c][k]: c<128 -> Wf[c][k] ; c>=128 -> Wf[c-128][128+k]
__global__ __launch_bounds__(256) void k_wconv(
    const float* __restrict__ Wf, short* __restrict__ wh, short* __restrict__ wl)
{
    int i = blockIdx.x * 256 + threadIdx.x;       // 0..32767
    if (i >= 256 * 128) return;
    int c = i >> 7, k = i & 127;
    float v = (c < 128) ? Wf[c * 256 + k] : Wf[(c - 128) * 256 + 128 + k];
    short h = f32_to_bf16_rne(v);
    wh[i] = h;
    wl[i] = f32_to_bf16_rne(v - bf16s_to_f32(h));
}

__global__ __launch_bounds__(256) void k_transform(
    const float* __restrict__ x, const short* __restrict__ wh,
    const short* __restrict__ wl, const float* __restrict__ bf,
    const float* __restrict__ Ww, const float* __restrict__ bw,
    float* __restrict__ U, float* __restrict__ Vb,
    double* __restrict__ p, double* __restrict__ q, int N)
{
    const int wv   = threadIdx.x >> 6;            // wave 0..3 -> col-tiles wv*4..+3
    const int lane = threadIdx.x & 63;
    const int r16  = lane & 15;                   // node index in tile / A-row
    const int kb   = lane >> 4;                   // k-block (8 elems)
    const int n0   = blockIdx.x * 16;             // 16-node tile
    const int nrow = n0 + r16;
    const int ncl  = (nrow < N) ? nrow : (N - 1);

    // ---- load this lane's x (B-operand) chunks: 4 k-tiles x 8 f32 ----
    float a_f[4][8];
    const float* xr = x + (size_t)ncl * 128 + kb * 8;
    #pragma unroll
    for (int kt = 0; kt < 4; ++kt) {
        f32x4 v0 = *(const f32x4*)(xr + kt * 32);
        f32x4 v1 = *(const f32x4*)(xr + kt * 32 + 4);
        a_f[kt][0] = v0.x; a_f[kt][1] = v0.y; a_f[kt][2] = v0.z; a_f[kt][3] = v0.w;
        a_f[kt][4] = v1.x; a_f[kt][5] = v1.y; a_f[kt][6] = v1.z; a_f[kt][7] = v1.w;
    }

    // ---- wave 0 only: fused p/q (f64), 4 partial chains each ----
    if (wv == 0) {
        double ps0 = 0.0, ps1 = 0.0, ps2 = 0.0, ps3 = 0.0;
        double qs0 = 0.0, qs1 = 0.0, qs2 = 0.0, qs3 = 0.0;
        #pragma unroll
        for (int kt = 0; kt < 4; ++kt) {
            #pragma unroll
            for (int j = 0; j < 8; j += 4) {
                int k = kt * 32 + kb * 8 + j;
                ps0 += (double)a_f[kt][j + 0] * (double)Ww[k + 0];
                ps1 += (double)a_f[kt][j + 1] * (double)Ww[k + 1];
                ps2 += (double)a_f[kt][j + 2] * (double)Ww[k + 2];
                ps3 += (double)a_f[kt][j + 3] * (double)Ww[k + 3];
                qs0 += (double)a_f[kt][j + 0] * (double)Ww[128 + k + 0];
                qs1 += (double)a_f[kt][j + 1] * (double)Ww[128 + k + 1];
                qs2 += (double)a_f[kt][j + 2] * (double)Ww[128 + k + 2];
                qs3 += (double)a_f[kt][j + 3] * (double)Ww[128 + k + 3];
            }
        }
        double ps = (ps0 + ps1) + (ps2 + ps3);
        double qs = (qs0 + qs1) + (qs2 + qs3);
        ps += __shfl_xor(ps, 16); ps += __shfl_xor(ps, 32);
        qs += __shfl_xor(qs, 16); qs += __shfl_xor(qs, 32);
        if (lane < 16 && nrow < N) {
            p[nrow] = ps;
            q[nrow] = qs + (double)bw[0];
        }
    }

    // ---- convert x to split bf16 fragments ----
    bf16x8 xh[4], xl[4];
    #pragma unroll
    for (int kt = 0; kt < 4; ++kt) {
        bf16x8 h, l;
        #pragma unroll
        for (int j = 0; j < 8; ++j) {
            float f = a_f[kt][j];
            short hs = f32_to_bf16_rne(f);
            h[j] = hs;
            l[j] = f32_to_bf16_rne(f - bf16s_to_f32(hs));
        }
        xh[kt] = h; xl[kt] = l;
    }

    // ---- this wave's 4 col-tiles: A=W' rows (ct*16+r16), B=x ----
    #pragma unroll
    for (int t = 0; t < 4; ++t) {
        const int ct = wv * 4 + t;
        const short* whr = wh + (size_t)(ct * 16 + r16) * 128 + kb * 8;
        const short* wlr = wl + (size_t)(ct * 16 + r16) * 128 + kb * 8;
        f32x4 ac0 = {0.f, 0.f, 0.f, 0.f};
        f32x4 ac1 = {0.f, 0.f, 0.f, 0.f};
        #pragma unroll
        for (int kt = 0; kt < 4; ++kt) {
            bf16x8 Wh = *(const bf16x8*)(whr + kt * 32);
            bf16x8 Wl = *(const bf16x8*)(wlr + kt * 32);
            ac0 = __builtin_amdgcn_mfma_f32_16x16x32_bf16(Wh, xh[kt], ac0, 0, 0, 0);
            ac1 = __builtin_amdgcn_mfma_f32_16x16x32_bf16(Wh, xl[kt], ac1, 0, 0, 0);
            ac0 = __builtin_amdgcn_mfma_f32_16x16x32_bf16(Wl, xh[kt], ac0, 0, 0, 0);
        }
        // D: col(lane&15)=node r16, row(kb*4+i)=W-col -> 4 consecutive cols
        f32x4 acc;
        acc[0] = ac0[0] + ac1[0]; acc[1] = ac0[1] + ac1[1];
        acc[2] = ac0[2] + ac1[2]; acc[3] = ac0[3] + ac1[3];
        if (nrow < N) {
            if (ct < 8) {
                *(f32x4*)(U + (size_t)nrow * 128 + ct * 16 + kb * 4) = acc;
            } else {
                f32x4 bias = *(const f32x4*)(bf + (ct - 8) * 16 + kb * 4);
                acc[0] += bias[0]; acc[1] += bias[1];
                acc[2] += bias[2]; acc[3] += bias[3];
                *(f32x4*)(Vb + (size_t)nrow * 128 + (ct - 8) * 16 + kb * 4) = acc;
            }
        }
    }
}

// ---------------- CSR build ----------------

__global__ __launch_bounds__(256) void k_hist(
    const int* __restrict__ tgt, int* __restrict__ counts, int E)
{
    int e = blockIdx.x * 256 + threadIdx.x;
    if (e < E) atomicAdd(&counts[tgt[e]], 1);
}

__global__ __launch_bounds__(256) void k_scan1(
    const int* __restrict__ counts, int* __restrict__ incl,
    int* __restrict__ partials, int N)
{
    __shared__ int sh[256];
    int t = threadIdx.x;
    int i = blockIdx.x * 256 + t;
    int v = (i < N) ? counts[i] : 0;
    sh[t] = v;
    __syncthreads();
    #pragma unroll
    for (int off = 1; off < 256; off <<= 1) {
        int add = (t >= off) ? sh[t - off] : 0;
        __syncthreads();
        sh[t] += add;
        __syncthreads();
    }
    if (i < N) incl[i] = sh[t];
    if (t == 255) partials[blockIdx.x] = sh[255];
}

__global__ __launch_bounds__(256) void k_scan2(int* __restrict__ partials, int nb)
{
    __shared__ int sh[256];
    int t = threadIdx.x;
    int v = (t < nb) ? partials[t] : 0;
    sh[t] = v;
    __syncthreads();
    #pragma unroll
    for (int off = 1; off < 256; off <<= 1) {
        int add = (t >= off) ? sh[t - off] : 0;
        __syncthreads();
        sh[t] += add;
        __syncthreads();
    }
    if (t < nb) partials[t] = sh[t] - v;   // exclusive
}

__global__ __launch_bounds__(256) void k_scan3(
    const int* __restrict__ counts, const int* __restrict__ incl,
    const int* __restrict__ partials, int* __restrict__ offsets,
    int* __restrict__ cursor, int N)
{
    int i = blockIdx.x * 256 + threadIdx.x;
    if (i >= N) return;
    int off = incl[i] - counts[i] + partials[i >> 8];
    offsets[i] = off;
    cursor[i]  = off;
}

__global__ __launch_bounds__(256) void k_scatter(
    const int* __restrict__ src, const int* __restrict__ tgt,
    int* __restrict__ cursor, int* __restrict__ srcs, int E)
{
    int e = blockIdx.x * 256 + threadIdx.x;
    if (e >= E) return;
    int pos = atomicAdd(&cursor[tgt[e]], 1);
    srcs[pos] = src[e];
}

// ------------- node aggregation: 32 lanes/node, 4-edge pipeline -------------

__global__ __launch_bounds__(256) void k_node(
    const float* __restrict__ U, const float* __restrict__ Vb,
    const double* __restrict__ p, const double* __restrict__ q,
    const int* __restrict__ offsets, const int* __restrict__ counts,
    const int* __restrict__ srcs, float* __restrict__ out, int N)
{
    int idx  = blockIdx.x * 256 + threadIdx.x;
    int n    = idx >> 5;                 // 32 lanes per node
    int lane = threadIdx.x & 31;
    if (n >= N) return;

    float4 Vn = ((const float4*)(Vb + (size_t)n * 128))[lane];
    double qn = q[n];                    // includes bw
    int beg = offsets[n];
    int cnt = counts[n];

    double ax = 0.0, ay = 0.0, az = 0.0, aw = 0.0, asum = 0.0;

    int i = 0;
    for (; i + 4 <= cnt; i += 4) {
        int s0 = srcs[beg + i + 0];
        int s1 = srcs[beg + i + 1];
        int s2 = srcs[beg + i + 2];
        int s3 = srcs[beg + i + 3];
        float4 U0 = ((const float4*)(U + (size_t)s0 * 128))[lane];
        float4 U1 = ((const float4*)(U + (size_t)s1 * 128))[lane];
        float4 U2 = ((const float4*)(U + (size_t)s2 * 128))[lane];
        float4 U3 = ((const float4*)(U + (size_t)s3 * 128))[lane];
        double a0 = p[s0] + qn, a1 = p[s1] + qn, a2 = p[s2] + qn, a3 = p[s3] + qn;
        float f0 = (float)a0, f1 = (float)a1, f2 = (float)a2, f3 = (float)a3;

        ax += (double)(fmaxf(U0.x + Vn.x, 0.f) * f0);
        ay += (double)(fmaxf(U0.y + Vn.y, 0.f) * f0);
        az += (double)(fmaxf(U0.z + Vn.z, 0.f) * f0);
        aw += (double)(fmaxf(U0.w + Vn.w, 0.f) * f0);
        asum += a0;
        ax += (double)(fmaxf(U1.x + Vn.x, 0.f) * f1);
        ay += (double)(fmaxf(U1.y + Vn.y, 0.f) * f1);
        az += (double)(fmaxf(U1.z + Vn.z, 0.f) * f1);
        aw += (double)(fmaxf(U1.w + Vn.w, 0.f) * f1);
        asum += a1;
        ax += (double)(fmaxf(U2.x + Vn.x, 0.f) * f2);
        ay += (double)(fmaxf(U2.y + Vn.y, 0.f) * f2);
        az += (double)(fmaxf(U2.z + Vn.z, 0.f) * f2);
        aw += (double)(fmaxf(U2.w + Vn.w, 0.f) * f2);
        asum += a2;
        ax += (double)(fmaxf(U3.x + Vn.x, 0.f) * f3);
        ay += (double)(fmaxf(U3.y + Vn.y, 0.f) * f3);
        az += (double)(fmaxf(U3.z + Vn.z, 0.f) * f3);
        aw += (double)(fmaxf(U3.w + Vn.w, 0.f) * f3);
        asum += a3;
    }
    for (; i < cnt; ++i) {
        int s = srcs[beg + i];
        float4 Ue = ((const float4*)(U + (size_t)s * 128))[lane];
        double a = p[s] + qn;
        float af = (float)a;
        ax += (double)(fmaxf(Ue.x + Vn.x, 0.f) * af);
        ay += (double)(fmaxf(Ue.y + Vn.y, 0.f) * af);
        az += (double)(fmaxf(Ue.z + Vn.z, 0.f) * af);
        aw += (double)(fmaxf(Ue.w + Vn.w, 0.f) * af);
        asum += a;
    }

    double inv = 1.0 / (asum + 1e-6);
    float4 o;
    o.x = (float)(ax * inv);
    o.y = (float)(ay * inv);
    o.z = (float)(az * inv);
    o.w = (float)(aw * inv);
    ((float4*)(out + (size_t)n * 128))[lane] = o;
}

extern "C" void kernel_launch(void* const* d_in, const int* in_sizes, int n_in,
                              void* d_out, int out_size, void* d_ws, size_t ws_size,
                              hipStream_t stream)
{
    const float* x   = (const float*)d_in[0];
    const float* Wf  = (const float*)d_in[1];
    const float* bf  = (const float*)d_in[2];
    const float* Ww  = (const float*)d_in[3];
    const float* bw  = (const float*)d_in[4];
    const int*   src = (const int*)d_in[5];
    const int*   tgt = (const int*)d_in[6];

    const int N = in_sizes[0] / 128;
    const int E = in_sizes[5];
    float* out = (float*)d_out;

    // workspace layout
    char* w = (char*)d_ws;
    float*  U        = (float*)w;                 w += (size_t)N * 128 * sizeof(float);
    float*  Vb       = (float*)w;                 w += (size_t)N * 128 * sizeof(float);
    double* p        = (double*)w;                w += (size_t)N * sizeof(double);
    double* q        = (double*)w;                w += (size_t)N * sizeof(double);
    int*    counts   = (int*)w;                   w += (size_t)N * sizeof(int);
    int*    incl     = (int*)w;                   w += (size_t)N * sizeof(int);
    int*    offsets  = (int*)w;                   w += (size_t)N * sizeof(int);
    int*    cursor   = (int*)w;                   w += (size_t)N * sizeof(int);
    int*    partials = (int*)w;                   w += 4096;
    int*    srcs     = (int*)w;                   w += (size_t)E * sizeof(int);
    short*  wh       = (short*)w;                 w += 256 * 128 * sizeof(short);
    short*  wl       = (short*)w;

    hipMemsetAsync(counts, 0, (size_t)N * sizeof(int), stream);

    k_wconv<<<128, 256, 0, stream>>>(Wf, wh, wl);
    k_transform<<<(N + 15) / 16, 256, 0, stream>>>(
        x, wh, wl, bf, Ww, bw, U, Vb, p, q, N);

    int ebk = (E + 255) / 256;
    int nbk = (N + 255) / 256;
    k_hist<<<ebk, 256, 0, stream>>>(tgt, counts, E);
    k_scan1<<<nbk, 256, 0, stream>>>(counts, incl, partials, N);
    k_scan2<<<1, 256, 0, stream>>>(partials, nbk);
    k_scan3<<<nbk, 256, 0, stream>>>(counts, incl, partials, offsets, cursor, N);
    k_scatter<<<ebk, 256, 0, stream>>>(src, tgt, cursor, srcs, E);

    long long nthreads = (long long)N * 32;
    k_node<<<(int)((nthreads + 255) / 256), 256, 0, stream>>>(
        U, Vb, p, q, offsets, counts, srcs, out, N);
}

// Round 7
// 272.460 us; speedup vs baseline: 1.1035x; 1.1035x over previous
//
#include <hip/hip_runtime.h>

// ---------------------------------------------------------------------------
// GAT edge-average layer, MI355X.
// Phase 0 : k_wconv — Wf -> split-bf16 W' tables PACKED IN MFMA FRAGMENT ORDER
//           whp/wlp[ct][kt][lane][8] so every B-load is 1KB contiguous.
// Phase 0b: k_pq — p[n]=x.w1, q[n]=x.w2+bw (f64, coalesced, 1 wave/node)
// Phase 1 : k_transform — 64-node tile; x staged via LDS (coalesced loads,
//           split-bf16 convert once, XOR-swizzled); MFMA bf16x3; C-stores
//           transposed through LDS -> fully coalesced global stores.
// Phase 2 : CSR build — histogram tgt, 2-level exclusive scan, scatter src
// Phase 3 : k_node — 32 lanes/node, 4-edge unrolled gather, f64 accum.
// ---------------------------------------------------------------------------

typedef short bf16x8 __attribute__((ext_vector_type(8)));
typedef short bf16x4 __attribute__((ext_vector_type(4)));
typedef float f32x4  __attribute__((ext_vector_type(4)));

__device__ inline short f32_to_bf16_rne(float f) {
    unsigned u = __float_as_uint(f);
    unsigned r = u + 0x7fffu + ((u >> 16) & 1u);
    return (short)(r >> 16);
}
__device__ inline float bf16s_to_f32(short s) {
    return __uint_as_float(((unsigned)(unsigned short)s) << 16);
}

// W'[c][k]: c<128 -> Wf[c][k] ; c>=128 -> Wf[c-128][128+k]
// Packed: whp[((ct*4+kt)*64+lane)*8 + j] = W'[ct*16+(lane&15)][kt*32+(lane>>4)*8+j]
__global__ __launch_bounds__(256) void k_wconv(
    const float* __restrict__ Wf, short* __restrict__ whp, short* __restrict__ wlp)
{
    int tid = blockIdx.x * 256 + threadIdx.x;     // 0..4095
    if (tid >= 4096) return;
    int ct = tid >> 8, kt = (tid >> 6) & 3, lane = tid & 63;
    int c = ct * 16 + (lane & 15);
    int kbase = kt * 32 + (lane >> 4) * 8;
    bf16x8 h, l;
    #pragma unroll
    for (int j = 0; j < 8; ++j) {
        int k = kbase + j;
        float v = (c < 128) ? Wf[c * 256 + k] : Wf[(c - 128) * 256 + 128 + k];
        short hs = f32_to_bf16_rne(v);
        h[j] = hs;
        l[j] = f32_to_bf16_rne(v - bf16s_to_f32(hs));
    }
    *(bf16x8*)(whp + (size_t)tid * 8) = h;
    *(bf16x8*)(wlp + (size_t)tid * 8) = l;
}

__global__ __launch_bounds__(256) void k_pq(
    const float* __restrict__ x, const float* __restrict__ Ww,
    const float* __restrict__ bw, double* __restrict__ p,
    double* __restrict__ q, int N)
{
    int wid  = (blockIdx.x * 256 + threadIdx.x) >> 6;   // one wave per node
    int lane = threadIdx.x & 63;
    if (wid >= N) return;
    const float* xr = x + (size_t)wid * 128;
    float x0 = xr[lane], x1 = xr[64 + lane];
    double ps = (double)x0 * (double)Ww[lane]       + (double)x1 * (double)Ww[64 + lane];
    double qs = (double)x0 * (double)Ww[128 + lane] + (double)x1 * (double)Ww[192 + lane];
    #pragma unroll
    for (int off = 32; off > 0; off >>= 1) {
        ps += __shfl_down(ps, off);
        qs += __shfl_down(qs, off);
    }
    if (lane == 0) { p[wid] = ps; q[wid] = qs + (double)bw[0]; }
}

__global__ __launch_bounds__(256) void k_transform(
    const float* __restrict__ x, const short* __restrict__ whp,
    const short* __restrict__ wlp, const float* __restrict__ bf,
    float* __restrict__ U, float* __restrict__ Vb, int N)
{
    __shared__ __attribute__((aligned(16))) char smem[32768];
    const int t = threadIdx.x, wv = t >> 6, lane = t & 63;
    const int n0 = blockIdx.x * 64;

    // ---- stage x -> split-bf16 LDS, XOR-swizzled (coalesced 1KB/instr) ----
    #pragma unroll
    for (int r = 0; r < 8; ++r) {
        int idx = r * 1024 + t * 4;              // f32 index in 64x128 tile
        int row = idx >> 7, col = idx & 127;
        int n = n0 + row;
        const float* sp = x + (size_t)((n < N) ? n : (N - 1)) * 128 + col;
        f32x4 v = *(const f32x4*)sp;
        bf16x4 hh, ll;
        #pragma unroll
        for (int j = 0; j < 4; ++j) {
            short hs = f32_to_bf16_rne(v[j]);
            hh[j] = hs;
            ll[j] = f32_to_bf16_rne(v[j] - bf16s_to_f32(hs));
        }
        int ba = (row * 256 + col * 2) ^ ((row & 7) << 4);
        *(bf16x4*)(smem + ba)         = hh;      // xh half
        *(bf16x4*)(smem + 16384 + ba) = ll;      // xl half
    }
    __syncthreads();

    // ---- compute: wave wv owns ct = wv*4 .. wv*4+3 ----
    f32x4 acc[4][4] = {};                        // [tt][nsub]
    #pragma unroll
    for (int tt = 0; tt < 4; ++tt) {
        const int ct = wv * 4 + tt;
        bf16x8 Wh[4], Wl[4];
        #pragma unroll
        for (int kt = 0; kt < 4; ++kt) {
            size_t off = (size_t)((ct * 4 + kt) * 64 + lane) * 8;
            Wh[kt] = *(const bf16x8*)(whp + off);    // 1KB contiguous per instr
            Wl[kt] = *(const bf16x8*)(wlp + off);
        }
        #pragma unroll
        for (int kt = 0; kt < 4; ++kt) {
            #pragma unroll
            for (int ns = 0; ns < 4; ++ns) {     // 4 independent dep-chains
                int row = ns * 16 + (lane & 15);
                int ba = (row * 256 + kt * 64 + (lane >> 4) * 16) ^ ((row & 7) << 4);
                bf16x8 xhf = *(const bf16x8*)(smem + ba);
                bf16x8 xlf = *(const bf16x8*)(smem + 16384 + ba);
                acc[tt][ns] = __builtin_amdgcn_mfma_f32_16x16x32_bf16(Wh[kt], xhf, acc[tt][ns], 0, 0, 0);
                acc[tt][ns] = __builtin_amdgcn_mfma_f32_16x16x32_bf16(Wh[kt], xlf, acc[tt][ns], 0, 0, 0);
                acc[tt][ns] = __builtin_amdgcn_mfma_f32_16x16x32_bf16(Wl[kt], xhf, acc[tt][ns], 0, 0, 0);
            }
        }
    }
    __syncthreads();

    // ---- epilogue pass 1: U (ct 0..7 = waves 0,1) via LDS transpose ----
    if (wv < 2) {
        #pragma unroll
        for (int tt = 0; tt < 4; ++tt) {
            int cb = (wv * 4 + tt) * 64 + (lane >> 4) * 16;  // byte col offset
            #pragma unroll
            for (int ns = 0; ns < 4; ++ns) {
                int node = ns * 16 + (lane & 15);
                int ba = (node * 512 + cb) ^ ((node & 7) << 4);
                *(f32x4*)(smem + ba) = acc[tt][ns];
            }
        }
    }
    __syncthreads();
    #pragma unroll
    for (int r = 0; r < 8; ++r) {
        int fo = r * 4096 + t * 16;              // byte offset in [64][512]
        int row = fo >> 9;
        if (n0 + row < N)
            *(f32x4*)(U + (size_t)(n0 + row) * 128 + ((fo & 511) >> 2)) =
                *(const f32x4*)(smem + (fo ^ ((row & 7) << 4)));
    }
    __syncthreads();

    // ---- epilogue pass 2: Vb = V + bf (ct 8..15 = waves 2,3) ----
    if (wv >= 2) {
        #pragma unroll
        for (int tt = 0; tt < 4; ++tt) {
            int cb = ((wv - 2) * 4 + tt) * 64 + (lane >> 4) * 16;
            #pragma unroll
            for (int ns = 0; ns < 4; ++ns) {
                int node = ns * 16 + (lane & 15);
                int ba = (node * 512 + cb) ^ ((node & 7) << 4);
                *(f32x4*)(smem + ba) = acc[tt][ns];
            }
        }
    }
    __syncthreads();
    #pragma unroll
    for (int r = 0; r < 8; ++r) {
        int fo = r * 4096 + t * 16;
        int row = fo >> 9;
        int col = (fo & 511) >> 2;
        if (n0 + row < N) {
            f32x4 v = *(const f32x4*)(smem + (fo ^ ((row & 7) << 4)));
            f32x4 bias = *(const f32x4*)(bf + col);
            v[0] += bias[0]; v[1] += bias[1]; v[2] += bias[2]; v[3] += bias[3];
            *(f32x4*)(Vb + (size_t)(n0 + row) * 128 + col) = v;
        }
    }
}

// ---------------- CSR build ----------------

__global__ __launch_bounds__(256) void k_hist(
    const int* __restrict__ tgt, int* __restrict__ counts, int E)
{
    int e = blockIdx.x * 256 + threadIdx.x;
    if (e < E) atomicAdd(&counts[tgt[e]], 1);
}

__global__ __launch_bounds__(256) void k_scan1(
    const int* __restrict__ counts, int* __restrict__ incl,
    int* __restrict__ partials, int N)
{
    __shared__ int sh[256];
    int t = threadIdx.x;
    int i = blockIdx.x * 256 + t;
    int v = (i < N) ? counts[i] : 0;
    sh[t] = v;
    __syncthreads();
    #pragma unroll
    for (int off = 1; off < 256; off <<= 1) {
        int add = (t >= off) ? sh[t - off] : 0;
        __syncthreads();
        sh[t] += add;
        __syncthreads();
    }
    if (i < N) incl[i] = sh[t];
    if (t == 255) partials[blockIdx.x] = sh[255];
}

__global__ __launch_bounds__(256) void k_scan2(int* __restrict__ partials, int nb)
{
    __shared__ int sh[256];
    int t = threadIdx.x;
    int v = (t < nb) ? partials[t] : 0;
    sh[t] = v;
    __syncthreads();
    #pragma unroll
    for (int off = 1; off < 256; off <<= 1) {
        int add = (t >= off) ? sh[t - off] : 0;
        __syncthreads();
        sh[t] += add;
        __syncthreads();
    }
    if (t < nb) partials[t] = sh[t] - v;   // exclusive
}

__global__ __launch_bounds__(256) void k_scan3(
    const int* __restrict__ counts, const int* __restrict__ incl,
    const int* __restrict__ partials, int* __restrict__ offsets,
    int* __restrict__ cursor, int N)
{
    int i = blockIdx.x * 256 + threadIdx.x;
    if (i >= N) return;
    int off = incl[i] - counts[i] + partials[i >> 8];
    offsets[i] = off;
    cursor[i]  = off;
}

__global__ __launch_bounds__(256) void k_scatter(
    const int* __restrict__ src, const int* __restrict__ tgt,
    int* __restrict__ cursor, int* __restrict__ srcs, int E)
{
    int e = blockIdx.x * 256 + threadIdx.x;
    if (e >= E) return;
    int pos = atomicAdd(&cursor[tgt[e]], 1);
    srcs[pos] = src[e];
}

// ------------- node aggregation: 32 lanes/node, 4-edge pipeline -------------

__global__ __launch_bounds__(256) void k_node(
    const float* __restrict__ U, const float* __restrict__ Vb,
    const double* __restrict__ p, const double* __restrict__ q,
    const int* __restrict__ offsets, const int* __restrict__ counts,
    const int* __restrict__ srcs, float* __restrict__ out, int N)
{
    int idx  = blockIdx.x * 256 + threadIdx.x;
    int n    = idx >> 5;                 // 32 lanes per node
    int lane = threadIdx.x & 31;
    if (n >= N) return;

    float4 Vn = ((const float4*)(Vb + (size_t)n * 128))[lane];
    double qn = q[n];                    // includes bw
    int beg = offsets[n];
    int cnt = counts[n];

    double ax = 0.0, ay = 0.0, az = 0.0, aw = 0.0, asum = 0.0;

    int i = 0;
    for (; i + 4 <= cnt; i += 4) {
        int s0 = srcs[beg + i + 0];
        int s1 = srcs[beg + i + 1];
        int s2 = srcs[beg + i + 2];
        int s3 = srcs[beg + i + 3];
        float4 U0 = ((const float4*)(U + (size_t)s0 * 128))[lane];
        float4 U1 = ((const float4*)(U + (size_t)s1 * 128))[lane];
        float4 U2 = ((const float4*)(U + (size_t)s2 * 128))[lane];
        float4 U3 = ((const float4*)(U + (size_t)s3 * 128))[lane];
        double a0 = p[s0] + qn, a1 = p[s1] + qn, a2 = p[s2] + qn, a3 = p[s3] + qn;
        float f0 = (float)a0, f1 = (float)a1, f2 = (float)a2, f3 = (float)a3;

        ax += (double)(fmaxf(U0.x + Vn.x, 0.f) * f0);
        ay += (double)(fmaxf(U0.y + Vn.y, 0.f) * f0);
        az += (double)(fmaxf(U0.z + Vn.z, 0.f) * f0);
        aw += (double)(fmaxf(U0.w + Vn.w, 0.f) * f0);
        asum += a0;
        ax += (double)(fmaxf(U1.x + Vn.x, 0.f) * f1);
        ay += (double)(fmaxf(U1.y + Vn.y, 0.f) * f1);
        az += (double)(fmaxf(U1.z + Vn.z, 0.f) * f1);
        aw += (double)(fmaxf(U1.w + Vn.w, 0.f) * f1);
        asum += a1;
        ax += (double)(fmaxf(U2.x + Vn.x, 0.f) * f2);
        ay += (double)(fmaxf(U2.y + Vn.y, 0.f) * f2);
        az += (double)(fmaxf(U2.z + Vn.z, 0.f) * f2);
        aw += (double)(fmaxf(U2.w + Vn.w, 0.f) * f2);
        asum += a2;
        ax += (double)(fmaxf(U3.x + Vn.x, 0.f) * f3);
        ay += (double)(fmaxf(U3.y + Vn.y, 0.f) * f3);
        az += (double)(fmaxf(U3.z + Vn.z, 0.f) * f3);
        aw += (double)(fmaxf(U3.w + Vn.w, 0.f) * f3);
        asum += a3;
    }
    for (; i < cnt; ++i) {
        int s = srcs[beg + i];
        float4 Ue = ((const float4*)(U + (size_t)s * 128))[lane];
        double a = p[s] + qn;
        float af = (float)a;
        ax += (double)(fmaxf(Ue.x + Vn.x, 0.f) * af);
        ay += (double)(fmaxf(Ue.y + Vn.y, 0.f) * af);
        az += (double)(fmaxf(Ue.z + Vn.z, 0.f) * af);
        aw += (double)(fmaxf(Ue.w + Vn.w, 0.f) * af);
        asum += a;
    }

    double inv = 1.0 / (asum + 1e-6);
    float4 o;
    o.x = (float)(ax * inv);
    o.y = (float)(ay * inv);
    o.z = (float)(az * inv);
    o.w = (float)(aw * inv);
    ((float4*)(out + (size_t)n * 128))[lane] = o;
}

extern "C" void kernel_launch(void* const* d_in, const int* in_sizes, int n_in,
                              void* d_out, int out_size, void* d_ws, size_t ws_size,
                              hipStream_t stream)
{
    const float* x   = (const float*)d_in[0];
    const float* Wf  = (const float*)d_in[1];
    const float* bf  = (const float*)d_in[2];
    const float* Ww  = (const float*)d_in[3];
    const float* bw  = (const float*)d_in[4];
    const int*   src = (const int*)d_in[5];
    const int*   tgt = (const int*)d_in[6];

    const int N = in_sizes[0] / 128;
    const int E = in_sizes[5];
    float* out = (float*)d_out;

    // workspace layout
    char* w = (char*)d_ws;
    float*  U        = (float*)w;                 w += (size_t)N * 128 * sizeof(float);
    float*  Vb       = (float*)w;                 w += (size_t)N * 128 * sizeof(float);
    double* p        = (double*)w;                w += (size_t)N * sizeof(double);
    double* q        = (double*)w;                w += (size_t)N * sizeof(double);
    int*    counts   = (int*)w;                   w += (size_t)N * sizeof(int);
    int*    incl     = (int*)w;                   w += (size_t)N * sizeof(int);
    int*    offsets  = (int*)w;                   w += (size_t)N * sizeof(int);
    int*    cursor   = (int*)w;                   w += (size_t)N * sizeof(int);
    int*    partials = (int*)w;                   w += 4096;
    int*    srcs     = (int*)w;                   w += (size_t)E * sizeof(int);
    short*  whp      = (short*)w;                 w += 256 * 128 * sizeof(short);
    short*  wlp      = (short*)w;

    hipMemsetAsync(counts, 0, (size_t)N * sizeof(int), stream);

    k_wconv<<<16, 256, 0, stream>>>(Wf, whp, wlp);
    k_pq<<<(N * 64 + 255) / 256, 256, 0, stream>>>(x, Ww, bw, p, q, N);
    k_transform<<<(N + 63) / 64, 256, 0, stream>>>(x, whp, wlp, bf, U, Vb, N);

    int ebk = (E + 255) / 256;
    int nbk = (N + 255) / 256;
    k_hist<<<ebk, 256, 0, stream>>>(tgt, counts, E);
    k_scan1<<<nbk, 256, 0, stream>>>(counts, incl, partials, N);
    k_scan2<<<1, 256, 0, stream>>>(partials, nbk);
    k_scan3<<<nbk, 256, 0, stream>>>(counts, incl, partials, offsets, cursor, N);
    k_scatter<<<ebk, 256, 0, stream>>>(src, tgt, cursor, srcs, E);

    long long nthreads = (long long)N * 32;
    k_node<<<(int)((nthreads + 255) / 256), 256, 0, stream>>>(
        U, Vb, p, q, offsets, counts, srcs, out, N);
}

// Round 8
// 252.028 us; speedup vs baseline: 1.1930x; 1.0811x over previous
//
#include <hip/hip_runtime.h>

// ---------------------------------------------------------------------------
// GAT edge-average layer, MI355X.
// Phase 0 : k_wconv — Wf -> split-bf16 W' tables packed in MFMA fragment order
// Phase 1 : k_transform — 64-node tile; x staged via LDS (split-bf16, XOR-
//           swizzled); MFMA bf16x3; U stored as **bf16** (halves k_node gather
//           bytes), Vb f32+bias; fused exact-f64 p/q from L2-warm x rows.
// Phase 2 : CSR build — histogram tgt, 2-level exclusive scan, scatter src
// Phase 3 : k_node — 32 lanes/node, 4-edge unrolled bf16 gather, f32 num /
//           f64 den accumulation, single float4 write per lane, no atomics.
// ---------------------------------------------------------------------------

typedef short bf16x8 __attribute__((ext_vector_type(8)));
typedef short bf16x4 __attribute__((ext_vector_type(4)));
typedef float f32x4  __attribute__((ext_vector_type(4)));

__device__ inline short f32_to_bf16_rne(float f) {
    unsigned u = __float_as_uint(f);
    unsigned r = u + 0x7fffu + ((u >> 16) & 1u);
    return (short)(r >> 16);
}
__device__ inline float bf16s_to_f32(short s) {
    return __uint_as_float(((unsigned)(unsigned short)s) << 16);
}

// W'[c][k]: c<128 -> Wf[c][k] ; c>=128 -> Wf[c-128][128+k]
// Packed: whp[((ct*4+kt)*64+lane)*8 + j] = W'[ct*16+(lane&15)][kt*32+(lane>>4)*8+j]
__global__ __launch_bounds__(256) void k_wconv(
    const float* __restrict__ Wf, short* __restrict__ whp, short* __restrict__ wlp)
{
    int tid = blockIdx.x * 256 + threadIdx.x;     // 0..4095
    if (tid >= 4096) return;
    int ct = tid >> 8, kt = (tid >> 6) & 3, lane = tid & 63;
    int c = ct * 16 + (lane & 15);
    int kbase = kt * 32 + (lane >> 4) * 8;
    bf16x8 h, l;
    #pragma unroll
    for (int j = 0; j < 8; ++j) {
        int k = kbase + j;
        float v = (c < 128) ? Wf[c * 256 + k] : Wf[(c - 128) * 256 + 128 + k];
        short hs = f32_to_bf16_rne(v);
        h[j] = hs;
        l[j] = f32_to_bf16_rne(v - bf16s_to_f32(hs));
    }
    *(bf16x8*)(whp + (size_t)tid * 8) = h;
    *(bf16x8*)(wlp + (size_t)tid * 8) = l;
}

__global__ __launch_bounds__(256) void k_transform(
    const float* __restrict__ x, const short* __restrict__ whp,
    const short* __restrict__ wlp, const float* __restrict__ bf,
    const float* __restrict__ Ww, const float* __restrict__ bw,
    short* __restrict__ Ub, float* __restrict__ Vb,
    double* __restrict__ p, double* __restrict__ q, int N)
{
    __shared__ __attribute__((aligned(16))) char smem[32768];
    const int t = threadIdx.x, wv = t >> 6, lane = t & 63;
    const int n0 = blockIdx.x * 64;

    // ---- stage x -> split-bf16 LDS, XOR-swizzled (coalesced 1KB/instr) ----
    #pragma unroll
    for (int r = 0; r < 8; ++r) {
        int idx = r * 1024 + t * 4;              // f32 index in 64x128 tile
        int row = idx >> 7, col = idx & 127;
        int n = n0 + row;
        const float* sp = x + (size_t)((n < N) ? n : (N - 1)) * 128 + col;
        f32x4 v = *(const f32x4*)sp;
        bf16x4 hh, ll;
        #pragma unroll
        for (int j = 0; j < 4; ++j) {
            short hs = f32_to_bf16_rne(v[j]);
            hh[j] = hs;
            ll[j] = f32_to_bf16_rne(v[j] - bf16s_to_f32(hs));
        }
        int ba = (row * 256 + col * 2) ^ ((row & 7) << 4);
        *(bf16x4*)(smem + ba)         = hh;      // xh half
        *(bf16x4*)(smem + 16384 + ba) = ll;      // xl half
    }

    // ---- fused exact-f64 p/q: 4 lanes per node row, x rows are L2-warm ----
    {
        int row = wv * 16 + (lane >> 2);         // 0..63
        int n = n0 + row;
        int c0 = (lane & 3) * 32;
        const float* xr = x + (size_t)((n < N) ? n : (N - 1)) * 128 + c0;
        double ps = 0.0, qs = 0.0;
        #pragma unroll
        for (int jj = 0; jj < 32; jj += 4) {
            f32x4 v = *(const f32x4*)(xr + jj);
            #pragma unroll
            for (int j = 0; j < 4; ++j) {
                ps += (double)v[j] * (double)Ww[c0 + jj + j];
                qs += (double)v[j] * (double)Ww[128 + c0 + jj + j];
            }
        }
        ps += __shfl_xor(ps, 1); ps += __shfl_xor(ps, 2);
        qs += __shfl_xor(qs, 1); qs += __shfl_xor(qs, 2);
        if ((lane & 3) == 0 && n < N) {
            p[n] = ps;
            q[n] = qs + (double)bw[0];
        }
    }
    __syncthreads();

    // ---- compute: wave wv owns ct = wv*4 .. wv*4+3 ----
    f32x4 acc[4][4] = {};                        // [tt][nsub]
    #pragma unroll
    for (int tt = 0; tt < 4; ++tt) {
        const int ct = wv * 4 + tt;
        bf16x8 Wh[4], Wl[4];
        #pragma unroll
        for (int kt = 0; kt < 4; ++kt) {
            size_t off = (size_t)((ct * 4 + kt) * 64 + lane) * 8;
            Wh[kt] = *(const bf16x8*)(whp + off);    // 1KB contiguous per instr
            Wl[kt] = *(const bf16x8*)(wlp + off);
        }
        #pragma unroll
        for (int kt = 0; kt < 4; ++kt) {
            #pragma unroll
            for (int ns = 0; ns < 4; ++ns) {     // 4 independent dep-chains
                int row = ns * 16 + (lane & 15);
                int ba = (row * 256 + kt * 64 + (lane >> 4) * 16) ^ ((row & 7) << 4);
                bf16x8 xhf = *(const bf16x8*)(smem + ba);
                bf16x8 xlf = *(const bf16x8*)(smem + 16384 + ba);
                acc[tt][ns] = __builtin_amdgcn_mfma_f32_16x16x32_bf16(Wh[kt], xhf, acc[tt][ns], 0, 0, 0);
                acc[tt][ns] = __builtin_amdgcn_mfma_f32_16x16x32_bf16(Wh[kt], xlf, acc[tt][ns], 0, 0, 0);
                acc[tt][ns] = __builtin_amdgcn_mfma_f32_16x16x32_bf16(Wl[kt], xhf, acc[tt][ns], 0, 0, 0);
            }
        }
    }
    __syncthreads();

    // ---- epilogue pass 1: U (ct 0..7 = waves 0,1) via LDS, store bf16 ----
    if (wv < 2) {
        #pragma unroll
        for (int tt = 0; tt < 4; ++tt) {
            int cb = (wv * 4 + tt) * 64 + (lane >> 4) * 16;  // byte col offset
            #pragma unroll
            for (int ns = 0; ns < 4; ++ns) {
                int node = ns * 16 + (lane & 15);
                int ba = (node * 512 + cb) ^ ((node & 7) << 4);
                *(f32x4*)(smem + ba) = acc[tt][ns];
            }
        }
    }
    __syncthreads();
    #pragma unroll
    for (int r = 0; r < 8; ++r) {
        int fo = r * 4096 + t * 16;              // byte offset in [64][512]
        int row = fo >> 9;
        int col = (fo & 511) >> 2;
        if (n0 + row < N) {
            f32x4 v = *(const f32x4*)(smem + (fo ^ ((row & 7) << 4)));
            bf16x4 b;
            b[0] = f32_to_bf16_rne(v[0]); b[1] = f32_to_bf16_rne(v[1]);
            b[2] = f32_to_bf16_rne(v[2]); b[3] = f32_to_bf16_rne(v[3]);
            *(bf16x4*)(Ub + (size_t)(n0 + row) * 128 + col) = b;
        }
    }
    __syncthreads();

    // ---- epilogue pass 2: Vb = V + bf (ct 8..15 = waves 2,3), f32 ----
    if (wv >= 2) {
        #pragma unroll
        for (int tt = 0; tt < 4; ++tt) {
            int cb = ((wv - 2) * 4 + tt) * 64 + (lane >> 4) * 16;
            #pragma unroll
            for (int ns = 0; ns < 4; ++ns) {
                int node = ns * 16 + (lane & 15);
                int ba = (node * 512 + cb) ^ ((node & 7) << 4);
                *(f32x4*)(smem + ba) = acc[tt][ns];
            }
        }
    }
    __syncthreads();
    #pragma unroll
    for (int r = 0; r < 8; ++r) {
        int fo = r * 4096 + t * 16;
        int row = fo >> 9;
        int col = (fo & 511) >> 2;
        if (n0 + row < N) {
            f32x4 v = *(const f32x4*)(smem + (fo ^ ((row & 7) << 4)));
            f32x4 bias = *(const f32x4*)(bf + col);
            v[0] += bias[0]; v[1] += bias[1]; v[2] += bias[2]; v[3] += bias[3];
            *(f32x4*)(Vb + (size_t)(n0 + row) * 128 + col) = v;
        }
    }
}

// ---------------- CSR build ----------------

__global__ __launch_bounds__(256) void k_hist(
    const int* __restrict__ tgt, int* __restrict__ counts, int E)
{
    int e = blockIdx.x * 256 + threadIdx.x;
    if (e < E) atomicAdd(&counts[tgt[e]], 1);
}

__global__ __launch_bounds__(256) void k_scan1(
    const int* __restrict__ counts, int* __restrict__ incl,
    int* __restrict__ partials, int N)
{
    __shared__ int sh[256];
    int t = threadIdx.x;
    int i = blockIdx.x * 256 + t;
    int v = (i < N) ? counts[i] : 0;
    sh[t] = v;
    __syncthreads();
    #pragma unroll
    for (int off = 1; off < 256; off <<= 1) {
        int add = (t >= off) ? sh[t - off] : 0;
        __syncthreads();
        sh[t] += add;
        __syncthreads();
    }
    if (i < N) incl[i] = sh[t];
    if (t == 255) partials[blockIdx.x] = sh[255];
}

__global__ __launch_bounds__(256) void k_scan2(int* __restrict__ partials, int nb)
{
    __shared__ int sh[256];
    int t = threadIdx.x;
    int v = (t < nb) ? partials[t] : 0;
    sh[t] = v;
    __syncthreads();
    #pragma unroll
    for (int off = 1; off < 256; off <<= 1) {
        int add = (t >= off) ? sh[t - off] : 0;
        __syncthreads();
        sh[t] += add;
        __syncthreads();
    }
    if (t < nb) partials[t] = sh[t] - v;   // exclusive
}

__global__ __launch_bounds__(256) void k_scan3(
    const int* __restrict__ counts, const int* __restrict__ incl,
    const int* __restrict__ partials, int* __restrict__ offsets,
    int* __restrict__ cursor, int N)
{
    int i = blockIdx.x * 256 + threadIdx.x;
    if (i >= N) return;
    int off = incl[i] - counts[i] + partials[i >> 8];
    offsets[i] = off;
    cursor[i]  = off;
}

__global__ __launch_bounds__(256) void k_scatter(
    const int* __restrict__ src, const int* __restrict__ tgt,
    int* __restrict__ cursor, int* __restrict__ srcs, int E)
{
    int e = blockIdx.x * 256 + threadIdx.x;
    if (e >= E) return;
    int pos = atomicAdd(&cursor[tgt[e]], 1);
    srcs[pos] = src[e];
}

// ------------- node aggregation: 32 lanes/node, bf16 U gathers -------------

__global__ __launch_bounds__(256) void k_node(
    const short* __restrict__ Ub, const float* __restrict__ Vb,
    const double* __restrict__ p, const double* __restrict__ q,
    const int* __restrict__ offsets, const int* __restrict__ counts,
    const int* __restrict__ srcs, float* __restrict__ out, int N)
{
    int idx  = blockIdx.x * 256 + threadIdx.x;
    int n    = idx >> 5;                 // 32 lanes per node
    int lane = threadIdx.x & 31;
    if (n >= N) return;

    float4 Vn = ((const float4*)(Vb + (size_t)n * 128))[lane];
    double qn = q[n];                    // includes bw
    int beg = offsets[n];
    int cnt = counts[n];

    float ax = 0.f, ay = 0.f, az = 0.f, aw = 0.f;
    double asum = 0.0;

    int i = 0;
    for (; i + 4 <= cnt; i += 4) {
        int s0 = srcs[beg + i + 0];
        int s1 = srcs[beg + i + 1];
        int s2 = srcs[beg + i + 2];
        int s3 = srcs[beg + i + 3];
        bf16x4 u0 = *(const bf16x4*)(Ub + (size_t)s0 * 128 + lane * 4);
        bf16x4 u1 = *(const bf16x4*)(Ub + (size_t)s1 * 128 + lane * 4);
        bf16x4 u2 = *(const bf16x4*)(Ub + (size_t)s2 * 128 + lane * 4);
        bf16x4 u3 = *(const bf16x4*)(Ub + (size_t)s3 * 128 + lane * 4);
        double a0 = p[s0] + qn, a1 = p[s1] + qn, a2 = p[s2] + qn, a3 = p[s3] + qn;
        float f0 = (float)a0, f1 = (float)a1, f2 = (float)a2, f3 = (float)a3;

        ax += fmaxf(bf16s_to_f32(u0[0]) + Vn.x, 0.f) * f0;
        ay += fmaxf(bf16s_to_f32(u0[1]) + Vn.y, 0.f) * f0;
        az += fmaxf(bf16s_to_f32(u0[2]) + Vn.z, 0.f) * f0;
        aw += fmaxf(bf16s_to_f32(u0[3]) + Vn.w, 0.f) * f0;
        asum += a0;
        ax += fmaxf(bf16s_to_f32(u1[0]) + Vn.x, 0.f) * f1;
        ay += fmaxf(bf16s_to_f32(u1[1]) + Vn.y, 0.f) * f1;
        az += fmaxf(bf16s_to_f32(u1[2]) + Vn.z, 0.f) * f1;
        aw += fmaxf(bf16s_to_f32(u1[3]) + Vn.w, 0.f) * f1;
        asum += a1;
        ax += fmaxf(bf16s_to_f32(u2[0]) + Vn.x, 0.f) * f2;
        ay += fmaxf(bf16s_to_f32(u2[1]) + Vn.y, 0.f) * f2;
        az += fmaxf(bf16s_to_f32(u2[2]) + Vn.z, 0.f) * f2;
        aw += fmaxf(bf16s_to_f32(u2[3]) + Vn.w, 0.f) * f2;
        asum += a2;
        ax += fmaxf(bf16s_to_f32(u3[0]) + Vn.x, 0.f) * f3;
        ay += fmaxf(bf16s_to_f32(u3[1]) + Vn.y, 0.f) * f3;
        az += fmaxf(bf16s_to_f32(u3[2]) + Vn.z, 0.f) * f3;
        aw += fmaxf(bf16s_to_f32(u3[3]) + Vn.w, 0.f) * f3;
        asum += a3;
    }
    for (; i < cnt; ++i) {
        int s = srcs[beg + i];
        bf16x4 u = *(const bf16x4*)(Ub + (size_t)s * 128 + lane * 4);
        double a = p[s] + qn;
        float af = (float)a;
        ax += fmaxf(bf16s_to_f32(u[0]) + Vn.x, 0.f) * af;
        ay += fmaxf(bf16s_to_f32(u[1]) + Vn.y, 0.f) * af;
        az += fmaxf(bf16s_to_f32(u[2]) + Vn.z, 0.f) * af;
        aw += fmaxf(bf16s_to_f32(u[3]) + Vn.w, 0.f) * af;
        asum += a;
    }

    double inv = 1.0 / (asum + 1e-6);
    float4 o;
    o.x = (float)((double)ax * inv);
    o.y = (float)((double)ay * inv);
    o.z = (float)((double)az * inv);
    o.w = (float)((double)aw * inv);
    ((float4*)(out + (size_t)n * 128))[lane] = o;
}

extern "C" void kernel_launch(void* const* d_in, const int* in_sizes, int n_in,
                              void* d_out, int out_size, void* d_ws, size_t ws_size,
                              hipStream_t stream)
{
    const float* x   = (const float*)d_in[0];
    const float* Wf  = (const float*)d_in[1];
    const float* bf  = (const float*)d_in[2];
    const float* Ww  = (const float*)d_in[3];
    const float* bw  = (const float*)d_in[4];
    const int*   src = (const int*)d_in[5];
    const int*   tgt = (const int*)d_in[6];

    const int N = in_sizes[0] / 128;
    const int E = in_sizes[5];
    float* out = (float*)d_out;

    // workspace layout
    char* w = (char*)d_ws;
    short*  Ub       = (short*)w;                 w += (size_t)N * 128 * sizeof(short);
    float*  Vb       = (float*)w;                 w += (size_t)N * 128 * sizeof(float);
    double* p        = (double*)w;                w += (size_t)N * sizeof(double);
    double* q        = (double*)w;                w += (size_t)N * sizeof(double);
    int*    counts   = (int*)w;                   w += (size_t)N * sizeof(int);
    int*    incl     = (int*)w;                   w += (size_t)N * sizeof(int);
    int*    offsets  = (int*)w;                   w += (size_t)N * sizeof(int);
    int*    cursor   = (int*)w;                   w += (size_t)N * sizeof(int);
    int*    partials = (int*)w;                   w += 4096;
    int*    srcs     = (int*)w;                   w += (size_t)E * sizeof(int);
    short*  whp      = (short*)w;                 w += 256 * 128 * sizeof(short);
    short*  wlp      = (short*)w;

    hipMemsetAsync(counts, 0, (size_t)N * sizeof(int), stream);

    k_wconv<<<16, 256, 0, stream>>>(Wf, whp, wlp);
    k_transform<<<(N + 63) / 64, 256, 0, stream>>>(
        x, whp, wlp, bf, Ww, bw, Ub, Vb, p, q, N);

    int ebk = (E + 255) / 256;
    int nbk = (N + 255) / 256;
    k_hist<<<ebk, 256, 0, stream>>>(tgt, counts, E);
    k_scan1<<<nbk, 256, 0, stream>>>(counts, incl, partials, N);
    k_scan2<<<1, 256, 0, stream>>>(partials, nbk);
    k_scan3<<<nbk, 256, 0, stream>>>(counts, incl, partials, offsets, cursor, N);
    k_scatter<<<ebk, 256, 0, stream>>>(src, tgt, cursor, srcs, E);

    long long nthreads = (long long)N * 32;
    k_node<<<(int)((nthreads + 255) / 256), 256, 0, stream>>>(
        Ub, Vb, p, q, offsets, counts, srcs, out, N);
}

// Round 9
// 238.223 us; speedup vs baseline: 1.2621x; 1.0579x over previous
//
#include <hip/hip_runtime.h>

// ---------------------------------------------------------------------------
// GAT edge-average layer, MI355X.
// Phase 0 : k_wconv — Wf -> split-bf16 W' tables packed in MFMA fragment order
// Phase 1 : k_transform — 64-node tile; x staged via LDS (split-bf16, XOR-
//           swizzled); MFMA bf16x3; U stored bf16, Vb f32+bias; fused f64 p/q.
// Phase 2 : CSR build — histogram tgt, 2-level scan, XCD-WINDOWED scatter
//           (each XCD scatters only its 1/8 node window -> L2-local writes,
//           no cross-XCD line churn; edge list re-read 8x sequentially).
// Phase 3 : k_node — 32 lanes/node, 4-edge unrolled bf16 gather, f32 num /
//           f64 den accumulation, single float4 write per lane, no atomics.
// ---------------------------------------------------------------------------

typedef short bf16x8 __attribute__((ext_vector_type(8)));
typedef short bf16x4 __attribute__((ext_vector_type(4)));
typedef float f32x4  __attribute__((ext_vector_type(4)));

__device__ inline short f32_to_bf16_rne(float f) {
    unsigned u = __float_as_uint(f);
    unsigned r = u + 0x7fffu + ((u >> 16) & 1u);
    return (short)(r >> 16);
}
__device__ inline float bf16s_to_f32(short s) {
    return __uint_as_float(((unsigned)(unsigned short)s) << 16);
}

// W'[c][k]: c<128 -> Wf[c][k] ; c>=128 -> Wf[c-128][128+k]
// Packed: whp[((ct*4+kt)*64+lane)*8 + j] = W'[ct*16+(lane&15)][kt*32+(lane>>4)*8+j]
__global__ __launch_bounds__(256) void k_wconv(
    const float* __restrict__ Wf, short* __restrict__ whp, short* __restrict__ wlp)
{
    int tid = blockIdx.x * 256 + threadIdx.x;     // 0..4095
    if (tid >= 4096) return;
    int ct = tid >> 8, kt = (tid >> 6) & 3, lane = tid & 63;
    int c = ct * 16 + (lane & 15);
    int kbase = kt * 32 + (lane >> 4) * 8;
    bf16x8 h, l;
    #pragma unroll
    for (int j = 0; j < 8; ++j) {
        int k = kbase + j;
        float v = (c < 128) ? Wf[c * 256 + k] : Wf[(c - 128) * 256 + 128 + k];
        short hs = f32_to_bf16_rne(v);
        h[j] = hs;
        l[j] = f32_to_bf16_rne(v - bf16s_to_f32(hs));
    }
    *(bf16x8*)(whp + (size_t)tid * 8) = h;
    *(bf16x8*)(wlp + (size_t)tid * 8) = l;
}

__global__ __launch_bounds__(256) void k_transform(
    const float* __restrict__ x, const short* __restrict__ whp,
    const short* __restrict__ wlp, const float* __restrict__ bf,
    const float* __restrict__ Ww, const float* __restrict__ bw,
    short* __restrict__ Ub, float* __restrict__ Vb,
    double* __restrict__ p, double* __restrict__ q, int N)
{
    __shared__ __attribute__((aligned(16))) char smem[32768];
    const int t = threadIdx.x, wv = t >> 6, lane = t & 63;
    const int n0 = blockIdx.x * 64;

    // ---- stage x -> split-bf16 LDS, XOR-swizzled (coalesced 1KB/instr) ----
    #pragma unroll
    for (int r = 0; r < 8; ++r) {
        int idx = r * 1024 + t * 4;              // f32 index in 64x128 tile
        int row = idx >> 7, col = idx & 127;
        int n = n0 + row;
        const float* sp = x + (size_t)((n < N) ? n : (N - 1)) * 128 + col;
        f32x4 v = *(const f32x4*)sp;
        bf16x4 hh, ll;
        #pragma unroll
        for (int j = 0; j < 4; ++j) {
            short hs = f32_to_bf16_rne(v[j]);
            hh[j] = hs;
            ll[j] = f32_to_bf16_rne(v[j] - bf16s_to_f32(hs));
        }
        int ba = (row * 256 + col * 2) ^ ((row & 7) << 4);
        *(bf16x4*)(smem + ba)         = hh;      // xh half
        *(bf16x4*)(smem + 16384 + ba) = ll;      // xl half
    }

    // ---- fused exact-f64 p/q: 4 lanes per node row, x rows are L2-warm ----
    {
        int row = wv * 16 + (lane >> 2);         // 0..63
        int n = n0 + row;
        int c0 = (lane & 3) * 32;
        const float* xr = x + (size_t)((n < N) ? n : (N - 1)) * 128 + c0;
        double ps = 0.0, qs = 0.0;
        #pragma unroll
        for (int jj = 0; jj < 32; jj += 4) {
            f32x4 v = *(const f32x4*)(xr + jj);
            #pragma unroll
            for (int j = 0; j < 4; ++j) {
                ps += (double)v[j] * (double)Ww[c0 + jj + j];
                qs += (double)v[j] * (double)Ww[128 + c0 + jj + j];
            }
        }
        ps += __shfl_xor(ps, 1); ps += __shfl_xor(ps, 2);
        qs += __shfl_xor(qs, 1); qs += __shfl_xor(qs, 2);
        if ((lane & 3) == 0 && n < N) {
            p[n] = ps;
            q[n] = qs + (double)bw[0];
        }
    }
    __syncthreads();

    // ---- compute: wave wv owns ct = wv*4 .. wv*4+3 ----
    f32x4 acc[4][4] = {};                        // [tt][nsub]
    #pragma unroll
    for (int tt = 0; tt < 4; ++tt) {
        const int ct = wv * 4 + tt;
        bf16x8 Wh[4], Wl[4];
        #pragma unroll
        for (int kt = 0; kt < 4; ++kt) {
            size_t off = (size_t)((ct * 4 + kt) * 64 + lane) * 8;
            Wh[kt] = *(const bf16x8*)(whp + off);    // 1KB contiguous per instr
            Wl[kt] = *(const bf16x8*)(wlp + off);
        }
        #pragma unroll
        for (int kt = 0; kt < 4; ++kt) {
            #pragma unroll
            for (int ns = 0; ns < 4; ++ns) {     // 4 independent dep-chains
                int row = ns * 16 + (lane & 15);
                int ba = (row * 256 + kt * 64 + (lane >> 4) * 16) ^ ((row & 7) << 4);
                bf16x8 xhf = *(const bf16x8*)(smem + ba);
                bf16x8 xlf = *(const bf16x8*)(smem + 16384 + ba);
                acc[tt][ns] = __builtin_amdgcn_mfma_f32_16x16x32_bf16(Wh[kt], xhf, acc[tt][ns], 0, 0, 0);
                acc[tt][ns] = __builtin_amdgcn_mfma_f32_16x16x32_bf16(Wh[kt], xlf, acc[tt][ns], 0, 0, 0);
                acc[tt][ns] = __builtin_amdgcn_mfma_f32_16x16x32_bf16(Wl[kt], xhf, acc[tt][ns], 0, 0, 0);
            }
        }
    }
    __syncthreads();

    // ---- epilogue pass 1: U (ct 0..7 = waves 0,1) via LDS, store bf16 ----
    if (wv < 2) {
        #pragma unroll
        for (int tt = 0; tt < 4; ++tt) {
            int cb = (wv * 4 + tt) * 64 + (lane >> 4) * 16;  // byte col offset
            #pragma unroll
            for (int ns = 0; ns < 4; ++ns) {
                int node = ns * 16 + (lane & 15);
                int ba = (node * 512 + cb) ^ ((node & 7) << 4);
                *(f32x4*)(smem + ba) = acc[tt][ns];
            }
        }
    }
    __syncthreads();
    #pragma unroll
    for (int r = 0; r < 8; ++r) {
        int fo = r * 4096 + t * 16;              // byte offset in [64][512]
        int row = fo >> 9;
        int col = (fo & 511) >> 2;
        if (n0 + row < N) {
            f32x4 v = *(const f32x4*)(smem + (fo ^ ((row & 7) << 4)));
            bf16x4 b;
            b[0] = f32_to_bf16_rne(v[0]); b[1] = f32_to_bf16_rne(v[1]);
            b[2] = f32_to_bf16_rne(v[2]); b[3] = f32_to_bf16_rne(v[3]);
            *(bf16x4*)(Ub + (size_t)(n0 + row) * 128 + col) = b;
        }
    }
    __syncthreads();

    // ---- epilogue pass 2: Vb = V + bf (ct 8..15 = waves 2,3), f32 ----
    if (wv >= 2) {
        #pragma unroll
        for (int tt = 0; tt < 4; ++tt) {
            int cb = ((wv - 2) * 4 + tt) * 64 + (lane >> 4) * 16;
            #pragma unroll
            for (int ns = 0; ns < 4; ++ns) {
                int node = ns * 16 + (lane & 15);
                int ba = (node * 512 + cb) ^ ((node & 7) << 4);
                *(f32x4*)(smem + ba) = acc[tt][ns];
            }
        }
    }
    __syncthreads();
    #pragma unroll
    for (int r = 0; r < 8; ++r) {
        int fo = r * 4096 + t * 16;
        int row = fo >> 9;
        int col = (fo & 511) >> 2;
        if (n0 + row < N) {
            f32x4 v = *(const f32x4*)(smem + (fo ^ ((row & 7) << 4)));
            f32x4 bias = *(const f32x4*)(bf + col);
            v[0] += bias[0]; v[1] += bias[1]; v[2] += bias[2]; v[3] += bias[3];
            *(f32x4*)(Vb + (size_t)(n0 + row) * 128 + col) = v;
        }
    }
}

// ---------------- CSR build ----------------

__global__ __launch_bounds__(256) void k_hist(
    const int* __restrict__ tgt, int* __restrict__ counts, int E)
{
    int e = blockIdx.x * 256 + threadIdx.x;
    if (e < E) atomicAdd(&counts[tgt[e]], 1);
}

__global__ __launch_bounds__(256) void k_scan1(
    const int* __restrict__ counts, int* __restrict__ incl,
    int* __restrict__ partials, int N)
{
    __shared__ int sh[256];
    int t = threadIdx.x;
    int i = blockIdx.x * 256 + t;
    int v = (i < N) ? counts[i] : 0;
    sh[t] = v;
    __syncthreads();
    #pragma unroll
    for (int off = 1; off < 256; off <<= 1) {
        int add = (t >= off) ? sh[t - off] : 0;
        __syncthreads();
        sh[t] += add;
        __syncthreads();
    }
    if (i < N) incl[i] = sh[t];
    if (t == 255) partials[blockIdx.x] = sh[255];
}

__global__ __launch_bounds__(256) void k_scan2(int* __restrict__ partials, int nb)
{
    __shared__ int sh[256];
    int t = threadIdx.x;
    int v = (t < nb) ? partials[t] : 0;
    sh[t] = v;
    __syncthreads();
    #pragma unroll
    for (int off = 1; off < 256; off <<= 1) {
        int add = (t >= off) ? sh[t - off] : 0;
        __syncthreads();
        sh[t] += add;
        __syncthreads();
    }
    if (t < nb) partials[t] = sh[t] - v;   // exclusive
}

__global__ __launch_bounds__(256) void k_scan3(
    const int* __restrict__ counts, const int* __restrict__ incl,
    const int* __restrict__ partials, int* __restrict__ offsets,
    int* __restrict__ cursor, int N)
{
    int i = blockIdx.x * 256 + threadIdx.x;
    if (i >= N) return;
    int off = incl[i] - counts[i] + partials[i >> 8];
    offsets[i] = off;
    cursor[i]  = off;
}

// XCD-windowed scatter: window w = blockIdx&7 -> XCD w (round-robin mapping).
// Each window only touches cursor/srcs for tgt in [w*wsz, (w+1)*wsz) ->
// write lines assembled inside ONE XCD's L2 (no cross-XCD churn).
__global__ __launch_bounds__(256) void k_scatter(
    const int* __restrict__ src, const int* __restrict__ tgt,
    int* __restrict__ cursor, int* __restrict__ srcs,
    int E, int wsz, int nchunk)
{
    const int win  = blockIdx.x & 7;
    const int step = gridDim.x >> 3;
    for (int c = blockIdx.x >> 3; c < nchunk; c += step) {
        int e = c * 256 + threadIdx.x;
        if (e < E) {
            int tg = tgt[e];
            if (tg / wsz == win) {
                int pos = atomicAdd(&cursor[tg], 1);
                srcs[pos] = src[e];
            }
        }
    }
}

// ------------- node aggregation: 32 lanes/node, bf16 U gathers -------------

__global__ __launch_bounds__(256) void k_node(
    const short* __restrict__ Ub, const float* __restrict__ Vb,
    const double* __restrict__ p, const double* __restrict__ q,
    const int* __restrict__ offsets, const int* __restrict__ counts,
    const int* __restrict__ srcs, float* __restrict__ out, int N)
{
    int idx  = blockIdx.x * 256 + threadIdx.x;
    int n    = idx >> 5;                 // 32 lanes per node
    int lane = threadIdx.x & 31;
    if (n >= N) return;

    float4 Vn = ((const float4*)(Vb + (size_t)n * 128))[lane];
    double qn = q[n];                    // includes bw
    int beg = offsets[n];
    int cnt = counts[n];

    float ax = 0.f, ay = 0.f, az = 0.f, aw = 0.f;
    double asum = 0.0;

    int i = 0;
    for (; i + 4 <= cnt; i += 4) {
        int s0 = srcs[beg + i + 0];
        int s1 = srcs[beg + i + 1];
        int s2 = srcs[beg + i + 2];
        int s3 = srcs[beg + i + 3];
        bf16x4 u0 = *(const bf16x4*)(Ub + (size_t)s0 * 128 + lane * 4);
        bf16x4 u1 = *(const bf16x4*)(Ub + (size_t)s1 * 128 + lane * 4);
        bf16x4 u2 = *(const bf16x4*)(Ub + (size_t)s2 * 128 + lane * 4);
        bf16x4 u3 = *(const bf16x4*)(Ub + (size_t)s3 * 128 + lane * 4);
        double a0 = p[s0] + qn, a1 = p[s1] + qn, a2 = p[s2] + qn, a3 = p[s3] + qn;
        float f0 = (float)a0, f1 = (float)a1, f2 = (float)a2, f3 = (float)a3;

        ax += fmaxf(bf16s_to_f32(u0[0]) + Vn.x, 0.f) * f0;
        ay += fmaxf(bf16s_to_f32(u0[1]) + Vn.y, 0.f) * f0;
        az += fmaxf(bf16s_to_f32(u0[2]) + Vn.z, 0.f) * f0;
        aw += fmaxf(bf16s_to_f32(u0[3]) + Vn.w, 0.f) * f0;
        asum += a0;
        ax += fmaxf(bf16s_to_f32(u1[0]) + Vn.x, 0.f) * f1;
        ay += fmaxf(bf16s_to_f32(u1[1]) + Vn.y, 0.f) * f1;
        az += fmaxf(bf16s_to_f32(u1[2]) + Vn.z, 0.f) * f1;
        aw += fmaxf(bf16s_to_f32(u1[3]) + Vn.w, 0.f) * f1;
        asum += a1;
        ax += fmaxf(bf16s_to_f32(u2[0]) + Vn.x, 0.f) * f2;
        ay += fmaxf(bf16s_to_f32(u2[1]) + Vn.y, 0.f) * f2;
        az += fmaxf(bf16s_to_f32(u2[2]) + Vn.z, 0.f) * f2;
        aw += fmaxf(bf16s_to_f32(u2[3]) + Vn.w, 0.f) * f2;
        asum += a2;
        ax += fmaxf(bf16s_to_f32(u3[0]) + Vn.x, 0.f) * f3;
        ay += fmaxf(bf16s_to_f32(u3[1]) + Vn.y, 0.f) * f3;
        az += fmaxf(bf16s_to_f32(u3[2]) + Vn.z, 0.f) * f3;
        aw += fmaxf(bf16s_to_f32(u3[3]) + Vn.w, 0.f) * f3;
        asum += a3;
    }
    for (; i < cnt; ++i) {
        int s = srcs[beg + i];
        bf16x4 u = *(const bf16x4*)(Ub + (size_t)s * 128 + lane * 4);
        double a = p[s] + qn;
        float af = (float)a;
        ax += fmaxf(bf16s_to_f32(u[0]) + Vn.x, 0.f) * af;
        ay += fmaxf(bf16s_to_f32(u[1]) + Vn.y, 0.f) * af;
        az += fmaxf(bf16s_to_f32(u[2]) + Vn.z, 0.f) * af;
        aw += fmaxf(bf16s_to_f32(u[3]) + Vn.w, 0.f) * af;
        asum += a;
    }

    double inv = 1.0 / (asum + 1e-6);
    float4 o;
    o.x = (float)((double)ax * inv);
    o.y = (float)((double)ay * inv);
    o.z = (float)((double)az * inv);
    o.w = (float)((double)aw * inv);
    ((float4*)(out + (size_t)n * 128))[lane] = o;
}

extern "C" void kernel_launch(void* const* d_in, const int* in_sizes, int n_in,
                              void* d_out, int out_size, void* d_ws, size_t ws_size,
                              hipStream_t stream)
{
    const float* x   = (const float*)d_in[0];
    const float* Wf  = (const float*)d_in[1];
    const float* bf  = (const float*)d_in[2];
    const float* Ww  = (const float*)d_in[3];
    const float* bw  = (const float*)d_in[4];
    const int*   src = (const int*)d_in[5];
    const int*   tgt = (const int*)d_in[6];

    const int N = in_sizes[0] / 128;
    const int E = in_sizes[5];
    float* out = (float*)d_out;

    // workspace layout
    char* w = (char*)d_ws;
    short*  Ub       = (short*)w;                 w += (size_t)N * 128 * sizeof(short);
    float*  Vb       = (float*)w;                 w += (size_t)N * 128 * sizeof(float);
    double* p        = (double*)w;                w += (size_t)N * sizeof(double);
    double* q        = (double*)w;                w += (size_t)N * sizeof(double);
    int*    counts   = (int*)w;                   w += (size_t)N * sizeof(int);
    int*    incl     = (int*)w;                   w += (size_t)N * sizeof(int);
    int*    offsets  = (int*)w;                   w += (size_t)N * sizeof(int);
    int*    cursor   = (int*)w;                   w += (size_t)N * sizeof(int);
    int*    partials = (int*)w;                   w += 4096;
    int*    srcs     = (int*)w;                   w += (size_t)E * sizeof(int);
    short*  whp      = (short*)w;                 w += 256 * 128 * sizeof(short);
    short*  wlp      = (short*)w;

    hipMemsetAsync(counts, 0, (size_t)N * sizeof(int), stream);

    k_wconv<<<16, 256, 0, stream>>>(Wf, whp, wlp);
    k_transform<<<(N + 63) / 64, 256, 0, stream>>>(
        x, whp, wlp, bf, Ww, bw, Ub, Vb, p, q, N);

    int ebk = (E + 255) / 256;
    int nbk = (N + 255) / 256;
    k_hist<<<ebk, 256, 0, stream>>>(tgt, counts, E);
    k_scan1<<<nbk, 256, 0, stream>>>(counts, incl, partials, N);
    k_scan2<<<1, 256, 0, stream>>>(partials, nbk);
    k_scan3<<<nbk, 256, 0, stream>>>(counts, incl, partials, offsets, cursor, N);

    int wsz = (N + 7) / 8;
    k_scatter<<<4096, 256, 0, stream>>>(src, tgt, cursor, srcs, E, wsz, ebk);

    long long nthreads = (long long)N * 32;
    k_node<<<(int)((nthreads + 255) / 256), 256, 0, stream>>>(
        Ub, Vb, p, q, offsets, counts, srcs, out, N);
}